// Round 1
// baseline (919.583 us; speedup 1.0000x reference)
//
#include <hip/hip_runtime.h>

#define DN 96
#define FIN 128
#define NB 8

// ---------- CSR build ----------

__global__ void hist_kernel(const int* __restrict__ ei, const float* __restrict__ ea,
                            int* __restrict__ cnt, int E, int N) {
    int e = blockIdx.x * 256 + threadIdx.x;
    if (e >= E) return;
    int dst = ei[E + e];
    int r = (ea[2 * e + 1] > ea[2 * e]) ? 1 : 0;  // argmax over 2, first-max tie -> 0
    atomicAdd(&cnt[r * N + dst], 1);
}

// Per-block exclusive scan + one atomic base per block: bins get contiguous
// segments (global order across blocks is irrelevant; we record rowstart per bin).
__global__ void offsets_kernel(const int* __restrict__ cnt, int* __restrict__ total,
                               int* __restrict__ rowstart, int* __restrict__ fillptr,
                               int nbins) {
    __shared__ int sd[256];
    __shared__ int sbase;
    int t = threadIdx.x;
    int b = blockIdx.x * 256 + t;
    int v = (b < nbins) ? cnt[b] : 0;
    sd[t] = v;
    __syncthreads();
    for (int off = 1; off < 256; off <<= 1) {
        int add = (t >= off) ? sd[t - off] : 0;
        __syncthreads();
        sd[t] += add;
        __syncthreads();
    }
    if (t == 255) sbase = atomicAdd(total, sd[255]);
    __syncthreads();
    if (b < nbins) {
        int s = sbase + sd[t] - v;  // exclusive
        rowstart[b] = s;
        fillptr[b] = s;
    }
}

__global__ void fill_kernel(const int* __restrict__ ei, const float* __restrict__ ea,
                            int* __restrict__ fillptr, int* __restrict__ srcs,
                            int E, int N) {
    int e = blockIdx.x * 256 + threadIdx.x;
    if (e >= E) return;
    int src = ei[e];
    int dst = ei[E + e];
    int r = (ea[2 * e + 1] > ea[2 * e]) ? 1 : 0;
    int pos = atomicAdd(&fillptr[r * N + dst], 1);
    srcs[pos] = src;
}

// ---------- Wf transpose: Wf[96][128] -> Wft[128][96] (coalesced reads later) ----------

__global__ void transpose_wf(const float* __restrict__ Wf, float* __restrict__ Wft) {
    int d = blockIdx.x;   // 0..95
    int k = threadIdx.x;  // 0..127
    Wft[k * DN + d] = Wf[d * FIN + k];
}

// ---------- initial linear: h = relu(x @ Wf^T + bf) ----------

__global__ void lin_kernel(const float* __restrict__ x, const float* __restrict__ Wft,
                           const float* __restrict__ bf, float* __restrict__ h, int N) {
    __shared__ __align__(16) float xl[NB * FIN];
    int t = threadIdx.x;
    int n0 = blockIdx.x * NB;
#pragma unroll
    for (int i = 0; i < NB; i++) {
        int n = n0 + i;
        if (n < N) xl[i * FIN + t] = x[(size_t)n * FIN + t];
    }
    __syncthreads();
    if (t < DN) {
        float acc[NB];
#pragma unroll
        for (int i = 0; i < NB; i++) acc[i] = bf[t];
        for (int k = 0; k < FIN; k += 4) {
            float w0 = Wft[(k + 0) * DN + t];
            float w1 = Wft[(k + 1) * DN + t];
            float w2 = Wft[(k + 2) * DN + t];
            float w3 = Wft[(k + 3) * DN + t];
#pragma unroll
            for (int i = 0; i < NB; i++) {
                float4 xv = *(const float4*)&xl[i * FIN + k];
                acc[i] += xv.x * w0 + xv.y * w1 + xv.z * w2 + xv.w * w3;
            }
        }
#pragma unroll
        for (int i = 0; i < NB; i++) {
            int n = n0 + i;
            if (n < N) {
                float v = acc[i];
                h[(size_t)n * DN + t] = v > 0.f ? v : 0.f;
            }
        }
    }
}

// ---------- fused RGCN conv: out = relu(h@root + bias + sum_r mean_r(h[src]) @ W[r]) ----------

__global__ void conv_kernel(const float* __restrict__ h, const float* __restrict__ root,
                            const float* __restrict__ W, const float* __restrict__ bias,
                            const int* __restrict__ rowstart, const int* __restrict__ cnt,
                            const int* __restrict__ srcs, float* __restrict__ out, int N) {
    __shared__ __align__(16) float hl[NB * DN];
    __shared__ __align__(16) float a0l[NB * DN];
    __shared__ __align__(16) float a1l[NB * DN];
    int t = threadIdx.x;
    int n0 = blockIdx.x * NB;

    if (t < DN) {
        for (int i = 0; i < NB; i++) {
            int n = n0 + i;
            if (n >= N) break;
            hl[i * DN + t] = h[(size_t)n * DN + t];
            float a0 = 0.f, a1 = 0.f;
            int s0 = rowstart[n], c0 = cnt[n];
            for (int e = 0; e < c0; e++) a0 += h[(size_t)srcs[s0 + e] * DN + t];
            int s1 = rowstart[N + n], c1 = cnt[N + n];
            for (int e = 0; e < c1; e++) a1 += h[(size_t)srcs[s1 + e] * DN + t];
            a0l[i * DN + t] = (c0 > 0) ? a0 / (float)c0 : 0.f;
            a1l[i * DN + t] = (c1 > 0) ? a1 / (float)c1 : 0.f;
        }
    }
    __syncthreads();
    if (t < DN) {
        const float* W0 = W;
        const float* W1 = W + DN * DN;
        float acc[NB];
#pragma unroll
        for (int i = 0; i < NB; i++) acc[i] = bias[t];
        for (int k = 0; k < DN; k += 4) {
            float r0 = root[(k + 0) * DN + t];
            float r1 = root[(k + 1) * DN + t];
            float r2 = root[(k + 2) * DN + t];
            float r3 = root[(k + 3) * DN + t];
            float u0 = W0[(k + 0) * DN + t];
            float u1 = W0[(k + 1) * DN + t];
            float u2 = W0[(k + 2) * DN + t];
            float u3 = W0[(k + 3) * DN + t];
            float v0 = W1[(k + 0) * DN + t];
            float v1 = W1[(k + 1) * DN + t];
            float v2 = W1[(k + 2) * DN + t];
            float v3 = W1[(k + 3) * DN + t];
#pragma unroll
            for (int i = 0; i < NB; i++) {
                float4 hv = *(const float4*)&hl[i * DN + k];
                float4 av = *(const float4*)&a0l[i * DN + k];
                float4 bv = *(const float4*)&a1l[i * DN + k];
                acc[i] += hv.x * r0 + hv.y * r1 + hv.z * r2 + hv.w * r3;
                acc[i] += av.x * u0 + av.y * u1 + av.z * u2 + av.w * u3;
                acc[i] += bv.x * v0 + bv.y * v1 + bv.z * v2 + bv.w * v3;
            }
        }
#pragma unroll
        for (int i = 0; i < NB; i++) {
            int n = n0 + i;
            if (n < N) {
                float v = acc[i];
                out[(size_t)n * DN + t] = v > 0.f ? v : 0.f;
            }
        }
    }
}

extern "C" void kernel_launch(void* const* d_in, const int* in_sizes, int n_in,
                              void* d_out, int out_size, void* d_ws, size_t ws_size,
                              hipStream_t stream) {
    const float* x    = (const float*)d_in[0];
    const int*   ei   = (const int*)d_in[1];
    const float* ea   = (const float*)d_in[2];
    const float* Wf   = (const float*)d_in[3];
    const float* bf   = (const float*)d_in[4];
    const float* W    = (const float*)d_in[5];
    const float* root = (const float*)d_in[6];
    const float* bias = (const float*)d_in[7];
    float* out = (float*)d_out;

    int N = in_sizes[0] / FIN;  // 50000
    int E = in_sizes[1] / 2;    // 800000
    int nbins = 2 * N;

    // ws layout (ints/floats, offsets in 4B elements, padded to keep 16B alignment)
    int* cnt      = (int*)d_ws;            // [2N]
    int* total    = cnt + nbins;           // [1] (contiguous with cnt for one memset)
    int* rowstart = cnt + nbins + 4;       // [2N]
    int* fillptr  = rowstart + nbins;      // [2N]
    int* srcs     = fillptr + nbins;       // [E]
    float* Wft    = (float*)(srcs + E);    // [128*96]
    float* hbuf   = Wft + FIN * DN;        // [N*96]

    hipMemsetAsync(cnt, 0, (size_t)(nbins + 1) * sizeof(int), stream);

    hist_kernel<<<(E + 255) / 256, 256, 0, stream>>>(ei, ea, cnt, E, N);
    offsets_kernel<<<(nbins + 255) / 256, 256, 0, stream>>>(cnt, total, rowstart, fillptr, nbins);
    fill_kernel<<<(E + 255) / 256, 256, 0, stream>>>(ei, ea, fillptr, srcs, E, N);
    transpose_wf<<<DN, FIN, 0, stream>>>(Wf, Wft);

    int nblk = (N + NB - 1) / NB;
    lin_kernel<<<nblk, 128, 0, stream>>>(x, Wft, bf, hbuf, N);

    // 3 conv layers, ping-pong hbuf <-> d_out (last one lands in d_out)
    conv_kernel<<<nblk, 128, 0, stream>>>(hbuf, root, W, bias, rowstart, cnt, srcs, out, N);
    conv_kernel<<<nblk, 128, 0, stream>>>(out, root, W, bias, rowstart, cnt, srcs, hbuf, N);
    conv_kernel<<<nblk, 128, 0, stream>>>(hbuf, root, W, bias, rowstart, cnt, srcs, out, N);
}

// Round 2
// 498.812 us; speedup vs baseline: 1.8435x; 1.8435x over previous
//
#include <hip/hip_runtime.h>

#define DN 96
#define FIN 128
#define NB 8   // nodes per conv block

struct __align__(4) F3 { float x, y, z; };

// ---------- CSR build ----------

__global__ void hist_kernel(const int* __restrict__ ei, const float* __restrict__ ea,
                            int* __restrict__ cnt, int E, int N) {
    int e = blockIdx.x * 256 + threadIdx.x;
    if (e >= E) return;
    int dst = ei[E + e];
    int r = (ea[2 * e + 1] > ea[2 * e]) ? 1 : 0;  // argmax over 2, first-max tie -> 0
    atomicAdd(&cnt[r * N + dst], 1);
}

__global__ void offsets_kernel(const int* __restrict__ cnt, int* __restrict__ total,
                               int* __restrict__ rowstart, int* __restrict__ fillptr,
                               int nbins) {
    __shared__ int sd[256];
    __shared__ int sbase;
    int t = threadIdx.x;
    int b = blockIdx.x * 256 + t;
    int v = (b < nbins) ? cnt[b] : 0;
    sd[t] = v;
    __syncthreads();
    for (int off = 1; off < 256; off <<= 1) {
        int add = (t >= off) ? sd[t - off] : 0;
        __syncthreads();
        sd[t] += add;
        __syncthreads();
    }
    if (t == 255) sbase = atomicAdd(total, sd[255]);
    __syncthreads();
    if (b < nbins) {
        int s = sbase + sd[t] - v;  // exclusive
        rowstart[b] = s;
        fillptr[b] = s;
    }
}

__global__ void fill_kernel(const int* __restrict__ ei, const float* __restrict__ ea,
                            int* __restrict__ fillptr, int* __restrict__ srcs,
                            int E, int N) {
    int e = blockIdx.x * 256 + threadIdx.x;
    if (e >= E) return;
    int src = ei[e];
    int dst = ei[E + e];
    int r = (ea[2 * e + 1] > ea[2 * e]) ? 1 : 0;
    int pos = atomicAdd(&fillptr[r * N + dst], 1);
    srcs[pos] = src;
}

// ---------- Wf transpose ----------

__global__ void transpose_wf(const float* __restrict__ Wf, float* __restrict__ Wft) {
    int d = blockIdx.x;   // 0..95
    int k = threadIdx.x;  // 0..127
    Wft[k * DN + d] = Wf[d * FIN + k];
}

// ---------- initial linear: h = relu(x @ Wf^T + bf) ----------

__global__ void lin_kernel(const float* __restrict__ x, const float* __restrict__ Wft,
                           const float* __restrict__ bf, float* __restrict__ h, int N) {
    __shared__ __align__(16) float xl[NB * FIN];
    int t = threadIdx.x;
    int n0 = blockIdx.x * NB;
#pragma unroll
    for (int i = 0; i < NB; i++) {
        int n = n0 + i;
        if (n < N) xl[i * FIN + t] = x[(size_t)n * FIN + t];
    }
    __syncthreads();
    if (t < DN) {
        float acc[NB];
#pragma unroll
        for (int i = 0; i < NB; i++) acc[i] = bf[t];
        for (int k = 0; k < FIN; k += 4) {
            float w0 = Wft[(k + 0) * DN + t];
            float w1 = Wft[(k + 1) * DN + t];
            float w2 = Wft[(k + 2) * DN + t];
            float w3 = Wft[(k + 3) * DN + t];
#pragma unroll
            for (int i = 0; i < NB; i++) {
                float4 xv = *(const float4*)&xl[i * FIN + k];
                acc[i] += xv.x * w0 + xv.y * w1 + xv.z * w2 + xv.w * w3;
            }
        }
#pragma unroll
        for (int i = 0; i < NB; i++) {
            int n = n0 + i;
            if (n < N) {
                float v = acc[i];
                h[(size_t)n * DN + t] = v > 0.f ? v : 0.f;
            }
        }
    }
}

// ---------- fused RGCN conv ----------
// Block = 256 threads. Phase 1: 8 half-waves, one node each; 32 lanes x float3
// = one full coalesced 384B row per edge; edge loop unrolled x4 for MLP.
// Phase 2: 2 groups of 96 threads, 4 node-accumulators each.

__device__ __forceinline__ F3 ldrow(const float* __restrict__ h, int src, int m) {
    return *(const F3*)(h + (size_t)src * DN + 3 * m);
}

__global__ void conv_kernel(const float* __restrict__ h, const float* __restrict__ root,
                            const float* __restrict__ W, const float* __restrict__ bias,
                            const int* __restrict__ rowstart, const int* __restrict__ cnt,
                            const int* __restrict__ srcs, float* __restrict__ out, int N) {
    __shared__ __align__(16) float hl[NB][DN];
    __shared__ __align__(16) float a0l[NB][DN];
    __shared__ __align__(16) float a1l[NB][DN];
    int t = threadIdx.x;
    int n0 = blockIdx.x * NB;

    // ---- phase 1: gather + mean ----
    {
        int hw = t >> 5;        // half-wave id: node slot 0..7
        int m  = t & 31;        // float3 slot within row
        int n = n0 + hw;
        if (n < N) {
            F3 hv = ldrow(h, n, m);
            hl[hw][3 * m + 0] = hv.x;
            hl[hw][3 * m + 1] = hv.y;
            hl[hw][3 * m + 2] = hv.z;
#pragma unroll
            for (int r = 0; r < 2; r++) {
                int base = rowstart[r * N + n];
                int c    = cnt[r * N + n];
                const int* sp = srcs + base;
                float ax = 0.f, ay = 0.f, az = 0.f;
                int e = 0;
                for (; e + 4 <= c; e += 4) {
                    int s0 = sp[e], s1 = sp[e + 1], s2 = sp[e + 2], s3 = sp[e + 3];
                    F3 v0 = ldrow(h, s0, m);
                    F3 v1 = ldrow(h, s1, m);
                    F3 v2 = ldrow(h, s2, m);
                    F3 v3 = ldrow(h, s3, m);
                    ax += (v0.x + v1.x) + (v2.x + v3.x);
                    ay += (v0.y + v1.y) + (v2.y + v3.y);
                    az += (v0.z + v1.z) + (v2.z + v3.z);
                }
                for (; e < c; e++) {
                    F3 v = ldrow(h, sp[e], m);
                    ax += v.x; ay += v.y; az += v.z;
                }
                float inv = (c > 0) ? 1.f / (float)c : 0.f;
                float* dstl = (r == 0) ? &a0l[hw][0] : &a1l[hw][0];
                dstl[3 * m + 0] = ax * inv;
                dstl[3 * m + 1] = ay * inv;
                dstl[3 * m + 2] = az * inv;
            }
        }
    }
    __syncthreads();

    // ---- phase 2: out = relu(hl@root + a0l@W0 + a1l@W1 + bias) ----
    if (t < 192) {
        int g  = t / DN;        // group 0 -> nodes 0..3, group 1 -> nodes 4..7
        int gt = t % DN;        // output component
        const float* W0 = W;
        const float* W1 = W + DN * DN;
        float acc[4];
        float bv = bias[gt];
#pragma unroll
        for (int i = 0; i < 4; i++) acc[i] = bv;
        for (int k = 0; k < DN; k += 4) {
            float r0 = root[(k + 0) * DN + gt];
            float r1 = root[(k + 1) * DN + gt];
            float r2 = root[(k + 2) * DN + gt];
            float r3 = root[(k + 3) * DN + gt];
            float u0 = W0[(k + 0) * DN + gt];
            float u1 = W0[(k + 1) * DN + gt];
            float u2 = W0[(k + 2) * DN + gt];
            float u3 = W0[(k + 3) * DN + gt];
            float v0 = W1[(k + 0) * DN + gt];
            float v1 = W1[(k + 1) * DN + gt];
            float v2 = W1[(k + 2) * DN + gt];
            float v3 = W1[(k + 3) * DN + gt];
#pragma unroll
            for (int i = 0; i < 4; i++) {
                int node = 4 * g + i;
                float4 hv = *(const float4*)&hl[node][k];
                float4 av = *(const float4*)&a0l[node][k];
                float4 cv = *(const float4*)&a1l[node][k];
                acc[i] += hv.x * r0 + hv.y * r1 + hv.z * r2 + hv.w * r3;
                acc[i] += av.x * u0 + av.y * u1 + av.z * u2 + av.w * u3;
                acc[i] += cv.x * v0 + cv.y * v1 + cv.z * v2 + cv.w * v3;
            }
        }
#pragma unroll
        for (int i = 0; i < 4; i++) {
            int n = n0 + 4 * g + i;
            if (n < N) {
                float v = acc[i];
                out[(size_t)n * DN + gt] = v > 0.f ? v : 0.f;
            }
        }
    }
}

extern "C" void kernel_launch(void* const* d_in, const int* in_sizes, int n_in,
                              void* d_out, int out_size, void* d_ws, size_t ws_size,
                              hipStream_t stream) {
    const float* x    = (const float*)d_in[0];
    const int*   ei   = (const int*)d_in[1];
    const float* ea   = (const float*)d_in[2];
    const float* Wf   = (const float*)d_in[3];
    const float* bf   = (const float*)d_in[4];
    const float* W    = (const float*)d_in[5];
    const float* root = (const float*)d_in[6];
    const float* bias = (const float*)d_in[7];
    float* out = (float*)d_out;

    int N = in_sizes[0] / FIN;  // 50000
    int E = in_sizes[1] / 2;    // 800000
    int nbins = 2 * N;

    int* cnt      = (int*)d_ws;            // [2N]
    int* total    = cnt + nbins;           // [1]
    int* rowstart = cnt + nbins + 4;       // [2N]
    int* fillptr  = rowstart + nbins;      // [2N]
    int* srcs     = fillptr + nbins;       // [E]
    float* Wft    = (float*)(srcs + E);    // [128*96]
    float* hbuf   = Wft + FIN * DN;        // [N*96]

    hipMemsetAsync(cnt, 0, (size_t)(nbins + 1) * sizeof(int), stream);

    hist_kernel<<<(E + 255) / 256, 256, 0, stream>>>(ei, ea, cnt, E, N);
    offsets_kernel<<<(nbins + 255) / 256, 256, 0, stream>>>(cnt, total, rowstart, fillptr, nbins);
    fill_kernel<<<(E + 255) / 256, 256, 0, stream>>>(ei, ea, fillptr, srcs, E, N);
    transpose_wf<<<DN, FIN, 0, stream>>>(Wf, Wft);

    int nblk = (N + NB - 1) / NB;
    lin_kernel<<<nblk, 128, 0, stream>>>(x, Wft, bf, hbuf, N);

    conv_kernel<<<nblk, 256, 0, stream>>>(hbuf, root, W, bias, rowstart, cnt, srcs, out, N);
    conv_kernel<<<nblk, 256, 0, stream>>>(out, root, W, bias, rowstart, cnt, srcs, hbuf, N);
    conv_kernel<<<nblk, 256, 0, stream>>>(hbuf, root, W, bias, rowstart, cnt, srcs, out, N);
}

// Round 3
// 474.061 us; speedup vs baseline: 1.9398x; 1.0522x over previous
//
#include <hip/hip_runtime.h>

#define DN 96
#define FIN 128
#define NB 8    // nodes per agg/lin block
#define GN 16   // nodes per gemm block

typedef unsigned int uint_t;
typedef unsigned short ushort_t;

__device__ __forceinline__ ushort_t f2bf(float f) {
    uint_t u = __float_as_uint(f);
    uint_t r = (u + 0x7FFFu + ((u >> 16) & 1u)) >> 16;
    return (ushort_t)r;
}
__device__ __forceinline__ float bf_lo(uint_t u) { return __uint_as_float(u << 16); }
__device__ __forceinline__ float bf_hi(uint_t u) { return __uint_as_float(u & 0xFFFF0000u); }

// ---------- CSR build ----------

__global__ void hist_kernel(const int* __restrict__ ei, const float* __restrict__ ea,
                            int* __restrict__ cnt, int E, int N) {
    int e = blockIdx.x * 256 + threadIdx.x;
    if (e >= E) return;
    int dst = ei[E + e];
    int r = (ea[2 * e + 1] > ea[2 * e]) ? 1 : 0;  // argmax over 2, first-max tie -> 0
    atomicAdd(&cnt[r * N + dst], 1);
}

__global__ void offsets_kernel(const int* __restrict__ cnt, int* __restrict__ total,
                               int* __restrict__ rowstart, int* __restrict__ fillptr,
                               int nbins) {
    __shared__ int sd[256];
    __shared__ int sbase;
    int t = threadIdx.x;
    int b = blockIdx.x * 256 + t;
    int v = (b < nbins) ? cnt[b] : 0;
    sd[t] = v;
    __syncthreads();
    for (int off = 1; off < 256; off <<= 1) {
        int add = (t >= off) ? sd[t - off] : 0;
        __syncthreads();
        sd[t] += add;
        __syncthreads();
    }
    if (t == 255) sbase = atomicAdd(total, sd[255]);
    __syncthreads();
    if (b < nbins) {
        int s = sbase + sd[t] - v;  // exclusive
        rowstart[b] = s;
        fillptr[b] = s;
    }
}

__global__ void fill_kernel(const int* __restrict__ ei, const float* __restrict__ ea,
                            int* __restrict__ fillptr, int* __restrict__ srcs,
                            int E, int N) {
    int e = blockIdx.x * 256 + threadIdx.x;
    if (e >= E) return;
    int src = ei[e];
    int dst = ei[E + e];
    int r = (ea[2 * e + 1] > ea[2 * e]) ? 1 : 0;
    int pos = atomicAdd(&fillptr[r * N + dst], 1);
    srcs[pos] = src;
}

// ---------- Wf transpose ----------

__global__ void transpose_wf(const float* __restrict__ Wf, float* __restrict__ Wft) {
    int d = blockIdx.x;   // 0..95
    int k = threadIdx.x;  // 0..127
    Wft[k * DN + d] = Wf[d * FIN + k];
}

// ---------- initial linear: h = relu(x @ Wf^T + bf) ----------

__global__ void lin_kernel(const float* __restrict__ x, const float* __restrict__ Wft,
                           const float* __restrict__ bf, float* __restrict__ h, int N) {
    __shared__ __align__(16) float xl[NB * FIN];
    int t = threadIdx.x;
    int n0 = blockIdx.x * NB;
#pragma unroll
    for (int i = 0; i < NB; i++) {
        int n = n0 + i;
        if (n < N) xl[i * FIN + t] = x[(size_t)n * FIN + t];
    }
    __syncthreads();
    if (t < DN) {
        float acc[NB];
#pragma unroll
        for (int i = 0; i < NB; i++) acc[i] = bf[t];
        for (int k = 0; k < FIN; k += 4) {
            float w0 = Wft[(k + 0) * DN + t];
            float w1 = Wft[(k + 1) * DN + t];
            float w2 = Wft[(k + 2) * DN + t];
            float w3 = Wft[(k + 3) * DN + t];
#pragma unroll
            for (int i = 0; i < NB; i++) {
                float4 xv = *(const float4*)&xl[i * FIN + k];
                acc[i] += xv.x * w0 + xv.y * w1 + xv.z * w2 + xv.w * w3;
            }
        }
#pragma unroll
        for (int i = 0; i < NB; i++) {
            int n = n0 + i;
            if (n < N) {
                float v = acc[i];
                h[(size_t)n * DN + t] = v > 0.f ? v : 0.f;
            }
        }
    }
}

// ---------- gemm: hroot = h@root + bias (in place over h); g0 = bf16(h@W0); g1 = bf16(h@W1) ----------
// In-place is safe: each block stages its own 16 rows to LDS, syncs, then rewrites only those rows.

__global__ __launch_bounds__(128) void gemm_kernel(float* hb, const float* __restrict__ root,
                            const float* __restrict__ W, const float* __restrict__ bias,
                            ushort_t* __restrict__ g0, ushort_t* __restrict__ g1, int N) {
    __shared__ __align__(16) float hl[GN][DN];
    int t = threadIdx.x;
    int n0 = blockIdx.x * GN;
    int nn = min(GN, N - n0);
    {
        const float4* s4 = (const float4*)(hb + (size_t)n0 * DN);
        float4* d4 = (float4*)&hl[0][0];
        int tot = nn * (DN / 4);
        for (int i = t; i < tot; i += 128) d4[i] = s4[i];
    }
    __syncthreads();
    if (t < DN) {
        const float* W0 = W;
        const float* W1 = W + DN * DN;
        float ar[GN], a0[GN], a1[GN];
        float bv = bias[t];
#pragma unroll
        for (int i = 0; i < GN; i++) { ar[i] = bv; a0[i] = 0.f; a1[i] = 0.f; }
        for (int k = 0; k < DN; k += 4) {
            float r0 = root[(k + 0) * DN + t];
            float r1 = root[(k + 1) * DN + t];
            float r2 = root[(k + 2) * DN + t];
            float r3 = root[(k + 3) * DN + t];
            float u0 = W0[(k + 0) * DN + t];
            float u1 = W0[(k + 1) * DN + t];
            float u2 = W0[(k + 2) * DN + t];
            float u3 = W0[(k + 3) * DN + t];
            float v0 = W1[(k + 0) * DN + t];
            float v1 = W1[(k + 1) * DN + t];
            float v2 = W1[(k + 2) * DN + t];
            float v3 = W1[(k + 3) * DN + t];
#pragma unroll
            for (int i = 0; i < GN; i++) {
                float4 hv = *(const float4*)&hl[i][k];
                ar[i] += hv.x * r0 + hv.y * r1 + hv.z * r2 + hv.w * r3;
                a0[i] += hv.x * u0 + hv.y * u1 + hv.z * u2 + hv.w * u3;
                a1[i] += hv.x * v0 + hv.y * v1 + hv.z * v2 + hv.w * v3;
            }
        }
        for (int i = 0; i < nn; i++) {
            size_t off = (size_t)(n0 + i) * DN + t;
            hb[off] = ar[i];
            g0[off] = f2bf(a0[i]);
            g1[off] = f2bf(a1[i]);
        }
    }
}

// ---------- agg: out[n] = relu(hroot[n] + mean(g0[src in r0]) + mean(g1[src in r1])) ----------
// hb holds hroot on entry, receives out (same rows, same thread -> in-place safe).
// 24 lanes per node, each lane owns 4 feature dims (one uint2 = 4 bf16 per edge row).

__global__ __launch_bounds__(256) void agg_kernel(float* hb, const uint_t* __restrict__ g0,
                           const uint_t* __restrict__ g1, const int* __restrict__ rowstart,
                           const int* __restrict__ cnt, const int* __restrict__ srcs, int N) {
    int t = threadIdx.x;
    int hw = t >> 5;
    int m = t & 31;
    int n = blockIdx.x * NB + hw;
    if (n >= N || m >= 24) return;

    size_t off = (size_t)n * DN + 4 * m;
    float4 hv = *(const float4*)(hb + off);   // issue early, consumed at the end

    int b0 = rowstart[n], c0 = cnt[n];
    int b1 = rowstart[N + n], c1 = cnt[N + n];

    float acc0 = 0.f, acc1 = 0.f, acc2 = 0.f, acc3 = 0.f;
#pragma unroll
    for (int r = 0; r < 2; r++) {
        const uint_t* g = r ? g1 : g0;
        int base = r ? b1 : b0;
        int c = r ? c1 : c0;
        const int* sp = srcs + base;
        float s0 = 0.f, s1 = 0.f, s2 = 0.f, s3 = 0.f;
        int e = 0;
        for (; e + 4 <= c; e += 4) {
            int i0 = sp[e], i1 = sp[e + 1], i2 = sp[e + 2], i3 = sp[e + 3];
            uint2 v0 = *(const uint2*)(g + (size_t)i0 * 48 + 2 * m);
            uint2 v1 = *(const uint2*)(g + (size_t)i1 * 48 + 2 * m);
            uint2 v2 = *(const uint2*)(g + (size_t)i2 * 48 + 2 * m);
            uint2 v3 = *(const uint2*)(g + (size_t)i3 * 48 + 2 * m);
            s0 += (bf_lo(v0.x) + bf_lo(v1.x)) + (bf_lo(v2.x) + bf_lo(v3.x));
            s1 += (bf_hi(v0.x) + bf_hi(v1.x)) + (bf_hi(v2.x) + bf_hi(v3.x));
            s2 += (bf_lo(v0.y) + bf_lo(v1.y)) + (bf_lo(v2.y) + bf_lo(v3.y));
            s3 += (bf_hi(v0.y) + bf_hi(v1.y)) + (bf_hi(v2.y) + bf_hi(v3.y));
        }
        for (; e < c; e++) {
            uint2 v = *(const uint2*)(g + (size_t)sp[e] * 48 + 2 * m);
            s0 += bf_lo(v.x);
            s1 += bf_hi(v.x);
            s2 += bf_lo(v.y);
            s3 += bf_hi(v.y);
        }
        float inv = (c > 0) ? 1.f / (float)c : 0.f;
        acc0 += s0 * inv;
        acc1 += s1 * inv;
        acc2 += s2 * inv;
        acc3 += s3 * inv;
    }
    float4 o;
    o.x = hv.x + acc0; o.x = o.x > 0.f ? o.x : 0.f;
    o.y = hv.y + acc1; o.y = o.y > 0.f ? o.y : 0.f;
    o.z = hv.z + acc2; o.z = o.z > 0.f ? o.z : 0.f;
    o.w = hv.w + acc3; o.w = o.w > 0.f ? o.w : 0.f;
    *(float4*)(hb + off) = o;
}

extern "C" void kernel_launch(void* const* d_in, const int* in_sizes, int n_in,
                              void* d_out, int out_size, void* d_ws, size_t ws_size,
                              hipStream_t stream) {
    const float* x    = (const float*)d_in[0];
    const int*   ei   = (const int*)d_in[1];
    const float* ea   = (const float*)d_in[2];
    const float* Wf   = (const float*)d_in[3];
    const float* bf   = (const float*)d_in[4];
    const float* W    = (const float*)d_in[5];
    const float* root = (const float*)d_in[6];
    const float* bias = (const float*)d_in[7];
    float* out = (float*)d_out;

    int N = in_sizes[0] / FIN;  // 50000
    int E = in_sizes[1] / 2;    // 800000
    int nbins = 2 * N;

    int* cnt      = (int*)d_ws;            // [2N]
    int* total    = cnt + nbins;           // [1]
    int* rowstart = cnt + nbins + 4;       // [2N]
    int* fillptr  = rowstart + nbins;      // [2N]
    int* srcs     = fillptr + nbins;       // [E]
    float* Wft    = (float*)(srcs + E);    // [128*96]
    ushort_t* g0  = (ushort_t*)(Wft + FIN * DN);  // [N*96] bf16
    ushort_t* g1  = g0 + (size_t)N * DN;          // [N*96] bf16

    hipMemsetAsync(cnt, 0, (size_t)(nbins + 1) * sizeof(int), stream);

    hist_kernel<<<(E + 255) / 256, 256, 0, stream>>>(ei, ea, cnt, E, N);
    offsets_kernel<<<(nbins + 255) / 256, 256, 0, stream>>>(cnt, total, rowstart, fillptr, nbins);
    fill_kernel<<<(E + 255) / 256, 256, 0, stream>>>(ei, ea, fillptr, srcs, E, N);
    transpose_wf<<<DN, FIN, 0, stream>>>(Wf, Wft);

    int nblk = (N + NB - 1) / NB;
    lin_kernel<<<nblk, 128, 0, stream>>>(x, Wft, bf, out, N);

    int gblk = (N + GN - 1) / GN;
#pragma unroll
    for (int l = 0; l < 3; l++) {
        gemm_kernel<<<gblk, 128, 0, stream>>>(out, root, W, bias, g0, g1, N);
        agg_kernel<<<nblk, 256, 0, stream>>>(out, (const uint_t*)g0, (const uint_t*)g1,
                                             rowstart, cnt, srcs, N);
    }
}

// Round 4
// 355.853 us; speedup vs baseline: 2.5842x; 1.3322x over previous
//
#include <hip/hip_runtime.h>

#define DN 96
#define FIN 128
#define NB 8    // nodes per agg/lin block

typedef unsigned int uint_t;
typedef unsigned short ushort_t;

typedef __attribute__((ext_vector_type(8))) short short8v;  // 8 bf16 (4 VGPRs)
typedef __attribute__((ext_vector_type(4))) float f32x4;

#define MFMA16 __builtin_amdgcn_mfma_f32_16x16x32_bf16

__device__ __forceinline__ ushort_t f2bf(float f) {
    uint_t u = __float_as_uint(f);
    uint_t r = (u + 0x7FFFu + ((u >> 16) & 1u)) >> 16;
    return (ushort_t)r;
}
__device__ __forceinline__ float bf2f(ushort_t h) { return __uint_as_float(((uint_t)h) << 16); }
__device__ __forceinline__ float bf_lo(uint_t u) { return __uint_as_float(u << 16); }
__device__ __forceinline__ float bf_hi(uint_t u) { return __uint_as_float(u & 0xFFFF0000u); }

// ---------- CSR build ----------

__global__ void hist_kernel(const int* __restrict__ ei, const float* __restrict__ ea,
                            int* __restrict__ cnt, int E, int N) {
    int e = blockIdx.x * 256 + threadIdx.x;
    if (e >= E) return;
    int dst = ei[E + e];
    int r = (ea[2 * e + 1] > ea[2 * e]) ? 1 : 0;  // argmax over 2, first-max tie -> 0
    atomicAdd(&cnt[r * N + dst], 1);
}

__global__ void offsets_kernel(const int* __restrict__ cnt, int* __restrict__ total,
                               int* __restrict__ rowstart, int* __restrict__ fillptr,
                               int nbins) {
    __shared__ int sd[256];
    __shared__ int sbase;
    int t = threadIdx.x;
    int b = blockIdx.x * 256 + t;
    int v = (b < nbins) ? cnt[b] : 0;
    sd[t] = v;
    __syncthreads();
    for (int off = 1; off < 256; off <<= 1) {
        int add = (t >= off) ? sd[t - off] : 0;
        __syncthreads();
        sd[t] += add;
        __syncthreads();
    }
    if (t == 255) sbase = atomicAdd(total, sd[255]);
    __syncthreads();
    if (b < nbins) {
        int s = sbase + sd[t] - v;  // exclusive
        rowstart[b] = s;
        fillptr[b] = s;
    }
}

__global__ void fill_kernel(const int* __restrict__ ei, const float* __restrict__ ea,
                            int* __restrict__ fillptr, int* __restrict__ srcs,
                            int E, int N) {
    int e = blockIdx.x * 256 + threadIdx.x;
    if (e >= E) return;
    int src = ei[e];
    int dst = ei[E + e];
    int r = (ea[2 * e + 1] > ea[2 * e]) ? 1 : 0;
    int pos = atomicAdd(&fillptr[r * N + dst], 1);
    srcs[pos] = src;
}

// ---------- Wf transpose ----------

__global__ void transpose_wf(const float* __restrict__ Wf, float* __restrict__ Wft) {
    int d = blockIdx.x;   // 0..95
    int k = threadIdx.x;  // 0..127
    Wft[k * DN + d] = Wf[d * FIN + k];
}

// ---------- initial linear: h = relu(x @ Wf^T + bf) ----------

__global__ void lin_kernel(const float* __restrict__ x, const float* __restrict__ Wft,
                           const float* __restrict__ bf, float* __restrict__ h, int N) {
    __shared__ __align__(16) float xl[NB * FIN];
    int t = threadIdx.x;
    int n0 = blockIdx.x * NB;
#pragma unroll
    for (int i = 0; i < NB; i++) {
        int n = n0 + i;
        if (n < N) xl[i * FIN + t] = x[(size_t)n * FIN + t];
    }
    __syncthreads();
    if (t < DN) {
        float acc[NB];
#pragma unroll
        for (int i = 0; i < NB; i++) acc[i] = bf[t];
        for (int k = 0; k < FIN; k += 4) {
            float w0 = Wft[(k + 0) * DN + t];
            float w1 = Wft[(k + 1) * DN + t];
            float w2 = Wft[(k + 2) * DN + t];
            float w3 = Wft[(k + 3) * DN + t];
#pragma unroll
            for (int i = 0; i < NB; i++) {
                float4 xv = *(const float4*)&xl[i * FIN + k];
                acc[i] += xv.x * w0 + xv.y * w1 + xv.z * w2 + xv.w * w3;
            }
        }
#pragma unroll
        for (int i = 0; i < NB; i++) {
            int n = n0 + i;
            if (n < N) {
                float v = acc[i];
                h[(size_t)n * DN + t] = v > 0.f ? v : 0.f;
            }
        }
    }
}

// ---------- weight pack: split bf16 hi/lo, MFMA B-fragment layout ----------
// frag id fid = ct*3 + ks; ct = mat*6 + cw (mat: 0=root,1=W0,2=W1), ks = k-step.
// Lane l of a frag holds B[k][col] for col = 16*cw + (l&15), k = 32*ks + (l>>4)*8 + j.
// Packed so each lane reads one contiguous 16B chunk: Bp[fid*512 + l*8 + j].

__global__ void pack_w(const float* __restrict__ root, const float* __restrict__ W,
                       ushort_t* __restrict__ Bph, ushort_t* __restrict__ Bpl) {
    int l = threadIdx.x;      // 0..63
    int fid = blockIdx.x;     // 0..53
    int ct = fid / 3, ks = fid % 3;
    int mat = ct / 6, cw = ct % 6;
    const float* M = (mat == 0) ? root : (W + (size_t)(mat - 1) * DN * DN);
    int k0 = 32 * ks + (l >> 4) * 8;
    int col = 16 * cw + (l & 15);
#pragma unroll
    for (int j = 0; j < 8; j++) {
        float v = M[(size_t)(k0 + j) * DN + col];
        ushort_t h = f2bf(v);
        size_t idx = ((size_t)fid * 64 + l) * 8 + j;
        Bph[idx] = h;
        Bpl[idx] = f2bf(v - bf2f(h));
    }
}

// ---------- gemm via MFMA: hroot = h@root + bias (in place); g0/g1 = bf16(h@W0/1) ----------
// One wave per 16 nodes. A split to hi/lo bf16 in regs (no LDS, no barrier).
// A*B = Ahi*Bhi + Ahi*Blo + Alo*Bhi (3 independent MFMA chains) ~ fp32 accuracy.
// In-place safe: wave reads exactly its 16 rows into regs before the first store.

__device__ __forceinline__ void cvt8(float4 x, float4 y, short8v& hi, short8v& lo) {
    union { short8v v; ushort_t u[8]; } H, L;
    float f[8] = {x.x, x.y, x.z, x.w, y.x, y.y, y.z, y.w};
#pragma unroll
    for (int j = 0; j < 8; j++) {
        ushort_t h = f2bf(f[j]);
        H.u[j] = h;
        L.u[j] = f2bf(f[j] - bf2f(h));
    }
    hi = H.v; lo = L.v;
}

__global__ __launch_bounds__(64) void gemm_mfma(float* hb,
                              const ushort_t* __restrict__ Bph, const ushort_t* __restrict__ Bpl,
                              ushort_t* __restrict__ g0, ushort_t* __restrict__ g1,
                              const float* __restrict__ bias, int N) {
    int l = threadIdx.x;          // 0..63
    int n0 = blockIdx.x * 16;
    int row = n0 + (l & 15);
    if (row >= N) row = N - 1;    // clamp; tail rows unused on store
    const float* hrow = hb + (size_t)row * DN + ((l >> 4) * 8);

    short8v ah[3], al[3];
#pragma unroll
    for (int ks = 0; ks < 3; ks++) {
        float4 x = *(const float4*)(hrow + 32 * ks);
        float4 y = *(const float4*)(hrow + 32 * ks + 4);
        cvt8(x, y, ah[ks], al[ks]);
    }

    for (int ct = 0; ct < 18; ct++) {
        f32x4 ahh = {0.f, 0.f, 0.f, 0.f};
        f32x4 ahl = {0.f, 0.f, 0.f, 0.f};
        f32x4 alh = {0.f, 0.f, 0.f, 0.f};
#pragma unroll
        for (int ks = 0; ks < 3; ks++) {
            const size_t base = ((size_t)(ct * 3 + ks) * 64 + l) * 8;
            short8v bh = *(const short8v*)(Bph + base);
            short8v bl = *(const short8v*)(Bpl + base);
            ahh = MFMA16(ah[ks], bh, ahh, 0, 0, 0);
            ahl = MFMA16(ah[ks], bl, ahl, 0, 0, 0);
            alh = MFMA16(al[ks], bh, alh, 0, 0, 0);
        }
        f32x4 acc = ahh + ahl + alh;

        int mat = ct / 6;                       // uniform across wave
        int col = (ct % 6) * 16 + (l & 15);
        int mb = n0 + ((l >> 4) << 2);
        if (mat == 0) {
            float bv = bias[col];
#pragma unroll
            for (int r = 0; r < 4; r++) {
                int m = mb + r;
                if (m < N) hb[(size_t)m * DN + col] = acc[r] + bv;
            }
        } else {
            ushort_t* g = (mat == 1) ? g0 : g1;
#pragma unroll
            for (int r = 0; r < 4; r++) {
                int m = mb + r;
                if (m < N) g[(size_t)m * DN + col] = f2bf(acc[r]);
            }
        }
    }
}

// ---------- agg: out[n] = relu(hroot[n] + mean(g0[src in r0]) + mean(g1[src in r1])) ----------

__global__ __launch_bounds__(256) void agg_kernel(float* hb, const uint_t* __restrict__ g0,
                           const uint_t* __restrict__ g1, const int* __restrict__ rowstart,
                           const int* __restrict__ cnt, const int* __restrict__ srcs, int N) {
    int t = threadIdx.x;
    int hw = t >> 5;
    int m = t & 31;
    int n = blockIdx.x * NB + hw;
    if (n >= N || m >= 24) return;

    size_t off = (size_t)n * DN + 4 * m;
    float4 hv = *(const float4*)(hb + off);

    int b0 = rowstart[n], c0 = cnt[n];
    int b1 = rowstart[N + n], c1 = cnt[N + n];

    float acc0 = 0.f, acc1 = 0.f, acc2 = 0.f, acc3 = 0.f;
#pragma unroll
    for (int r = 0; r < 2; r++) {
        const uint_t* g = r ? g1 : g0;
        int base = r ? b1 : b0;
        int c = r ? c1 : c0;
        const int* sp = srcs + base;
        float s0 = 0.f, s1 = 0.f, s2 = 0.f, s3 = 0.f;
        int e = 0;
        for (; e + 4 <= c; e += 4) {
            int i0 = sp[e], i1 = sp[e + 1], i2 = sp[e + 2], i3 = sp[e + 3];
            uint2 v0 = *(const uint2*)(g + (size_t)i0 * 48 + 2 * m);
            uint2 v1 = *(const uint2*)(g + (size_t)i1 * 48 + 2 * m);
            uint2 v2 = *(const uint2*)(g + (size_t)i2 * 48 + 2 * m);
            uint2 v3 = *(const uint2*)(g + (size_t)i3 * 48 + 2 * m);
            s0 += (bf_lo(v0.x) + bf_lo(v1.x)) + (bf_lo(v2.x) + bf_lo(v3.x));
            s1 += (bf_hi(v0.x) + bf_hi(v1.x)) + (bf_hi(v2.x) + bf_hi(v3.x));
            s2 += (bf_lo(v0.y) + bf_lo(v1.y)) + (bf_lo(v2.y) + bf_lo(v3.y));
            s3 += (bf_hi(v0.y) + bf_hi(v1.y)) + (bf_hi(v2.y) + bf_hi(v3.y));
        }
        for (; e < c; e++) {
            uint2 v = *(const uint2*)(g + (size_t)sp[e] * 48 + 2 * m);
            s0 += bf_lo(v.x);
            s1 += bf_hi(v.x);
            s2 += bf_lo(v.y);
            s3 += bf_hi(v.y);
        }
        float inv = (c > 0) ? 1.f / (float)c : 0.f;
        acc0 += s0 * inv;
        acc1 += s1 * inv;
        acc2 += s2 * inv;
        acc3 += s3 * inv;
    }
    float4 o;
    o.x = hv.x + acc0; o.x = o.x > 0.f ? o.x : 0.f;
    o.y = hv.y + acc1; o.y = o.y > 0.f ? o.y : 0.f;
    o.z = hv.z + acc2; o.z = o.z > 0.f ? o.z : 0.f;
    o.w = hv.w + acc3; o.w = o.w > 0.f ? o.w : 0.f;
    *(float4*)(hb + off) = o;
}

extern "C" void kernel_launch(void* const* d_in, const int* in_sizes, int n_in,
                              void* d_out, int out_size, void* d_ws, size_t ws_size,
                              hipStream_t stream) {
    const float* x    = (const float*)d_in[0];
    const int*   ei   = (const int*)d_in[1];
    const float* ea   = (const float*)d_in[2];
    const float* Wf   = (const float*)d_in[3];
    const float* bf   = (const float*)d_in[4];
    const float* W    = (const float*)d_in[5];
    const float* root = (const float*)d_in[6];
    const float* bias = (const float*)d_in[7];
    float* out = (float*)d_out;

    int N = in_sizes[0] / FIN;  // 50000
    int E = in_sizes[1] / 2;    // 800000
    int nbins = 2 * N;

    int* cnt      = (int*)d_ws;            // [2N]
    int* total    = cnt + nbins;           // [1]
    int* rowstart = cnt + nbins + 4;       // [2N]
    int* fillptr  = rowstart + nbins;      // [2N]
    int* srcs     = fillptr + nbins;       // [E]
    float* Wft    = (float*)(srcs + E);    // [128*96]
    ushort_t* Bph = (ushort_t*)(Wft + FIN * DN);   // [54*64*8]
    ushort_t* Bpl = Bph + 54 * 64 * 8;             // [54*64*8]
    ushort_t* g0  = Bpl + 54 * 64 * 8;             // [N*96] bf16
    ushort_t* g1  = g0 + (size_t)N * DN;           // [N*96] bf16

    hipMemsetAsync(cnt, 0, (size_t)(nbins + 1) * sizeof(int), stream);

    hist_kernel<<<(E + 255) / 256, 256, 0, stream>>>(ei, ea, cnt, E, N);
    offsets_kernel<<<(nbins + 255) / 256, 256, 0, stream>>>(cnt, total, rowstart, fillptr, nbins);
    fill_kernel<<<(E + 255) / 256, 256, 0, stream>>>(ei, ea, fillptr, srcs, E, N);
    transpose_wf<<<DN, FIN, 0, stream>>>(Wf, Wft);
    pack_w<<<54, 64, 0, stream>>>(root, W, Bph, Bpl);

    int nblk = (N + NB - 1) / NB;
    lin_kernel<<<nblk, 128, 0, stream>>>(x, Wft, bf, out, N);

    int gblk = (N + 15) / 16;
    for (int lyr = 0; lyr < 3; lyr++) {
        gemm_mfma<<<gblk, 64, 0, stream>>>(out, Bph, Bpl, g0, g1, bias, N);
        agg_kernel<<<nblk, 256, 0, stream>>>(out, (const uint_t*)g0, (const uint_t*)g1,
                                             rowstart, cnt, srcs, N);
    }
}

// Round 5
// 319.608 us; speedup vs baseline: 2.8772x; 1.1134x over previous
//
#include <hip/hip_runtime.h>

#define DN 96
#define FIN 128
#define NB 8    // nodes per agg block

typedef unsigned int uint_t;
typedef unsigned short ushort_t;

typedef __attribute__((ext_vector_type(8))) short short8v;  // 8 bf16 (4 VGPRs)
typedef __attribute__((ext_vector_type(4))) float f32x4;

#define MFMA16 __builtin_amdgcn_mfma_f32_16x16x32_bf16

__device__ __forceinline__ ushort_t f2bf(float f) {
    uint_t u = __float_as_uint(f);
    uint_t r = (u + 0x7FFFu + ((u >> 16) & 1u)) >> 16;
    return (ushort_t)r;
}
__device__ __forceinline__ float bf2f(ushort_t h) { return __uint_as_float(((uint_t)h) << 16); }
__device__ __forceinline__ float bf_lo(uint_t u) { return __uint_as_float(u << 16); }
__device__ __forceinline__ float bf_hi(uint_t u) { return __uint_as_float(u & 0xFFFF0000u); }

// ---------- CSR build ----------
// hist: count per (rel,dst) bin; also emit packed kd[e] = {dst | r<<16, src}
// (N < 65536 so src/dst fit in 16 bits).

__global__ void hist_kernel(const int* __restrict__ ei, const float* __restrict__ ea,
                            int* __restrict__ cnt, uint2* __restrict__ kd, int E, int N) {
    int e = blockIdx.x * 256 + threadIdx.x;
    if (e >= E) return;
    int src = ei[e];
    int dst = ei[E + e];
    int r = (ea[2 * e + 1] > ea[2 * e]) ? 1 : 0;  // argmax over 2, first-max tie -> 0
    kd[e] = make_uint2((uint_t)dst | ((uint_t)r << 16), (uint_t)src);
    atomicAdd(&cnt[r * N + dst], 1);
}

__global__ void offsets_kernel(const int* __restrict__ cnt, int* __restrict__ total,
                               int* __restrict__ rowstart, int* __restrict__ fillptr,
                               int nbins) {
    __shared__ int sd[256];
    __shared__ int sbase;
    int t = threadIdx.x;
    int b = blockIdx.x * 256 + t;
    int v = (b < nbins) ? cnt[b] : 0;
    sd[t] = v;
    __syncthreads();
    for (int off = 1; off < 256; off <<= 1) {
        int add = (t >= off) ? sd[t - off] : 0;
        __syncthreads();
        sd[t] += add;
        __syncthreads();
    }
    if (t == 255) sbase = atomicAdd(total, sd[255]);
    __syncthreads();
    if (b < nbins) {
        int s = sbase + sd[t] - v;  // exclusive
        rowstart[b] = s;
        fillptr[b] = s;
    }
}

// XCD-partitioned fill: blockIdx = chunk*8 + p. Block processes its edge chunk
// but only edges with dst in partition p -> srcs writes for a dst range come
// from (heuristically) one XCD -> full-line L2 writebacks, no 64B/4B
// amplification. kd reads are L2/L3-resident.

__global__ __launch_bounds__(256) void fill_part(const uint2* __restrict__ kd,
                            int* __restrict__ fillptr, int* __restrict__ srcs,
                            int E, int N, int PS) {
    int p = blockIdx.x & 7;
    int c = blockIdx.x >> 3;
    int base = c * 2048 + threadIdx.x;
#pragma unroll
    for (int i = 0; i < 8; i++) {
        int e = base + i * 256;
        if (e < E) {
            uint2 v = kd[e];
            int dst = v.x & 0xFFFF;
            if (dst / PS == p) {
                int r = (v.x >> 16) & 1;
                int pos = atomicAdd(&fillptr[r * N + dst], 1);
                srcs[pos] = (int)v.y;
            }
        }
    }
}

// ---------- weight pack: split bf16 hi/lo, MFMA B-fragment layout ----------
// Lane l of a frag holds B[k][col], col = 16*cw + (l&15), k = 32*ks + (l>>4)*8 + j,
// packed so each lane reads one contiguous 16B chunk.

// conv weights: fid = ct*3 + ks; ct = mat*6 + cw (0=root,1=W0,2=W1); B = M (row-major [k][col])
__global__ void pack_w(const float* __restrict__ root, const float* __restrict__ W,
                       ushort_t* __restrict__ Bph, ushort_t* __restrict__ Bpl) {
    int l = threadIdx.x;      // 0..63
    int fid = blockIdx.x;     // 0..53
    int ct = fid / 3, ks = fid % 3;
    int mat = ct / 6, cw = ct % 6;
    const float* M = (mat == 0) ? root : (W + (size_t)(mat - 1) * DN * DN);
    int k0 = 32 * ks + (l >> 4) * 8;
    int col = 16 * cw + (l & 15);
#pragma unroll
    for (int j = 0; j < 8; j++) {
        float v = M[(size_t)(k0 + j) * DN + col];
        ushort_t h = f2bf(v);
        size_t idx = ((size_t)fid * 64 + l) * 8 + j;
        Bph[idx] = h;
        Bpl[idx] = f2bf(v - bf2f(h));
    }
}

// lin weights: B[k][col] = Wf[col][k] (h = x @ Wf^T). fid = ct*4 + ks; ct 0..5, ks 0..3.
__global__ void pack_wf(const float* __restrict__ Wf, ushort_t* __restrict__ Wfh,
                        ushort_t* __restrict__ Wfl) {
    int l = threadIdx.x;      // 0..63
    int fid = blockIdx.x;     // 0..23
    int ct = fid >> 2, ks = fid & 3;
    int k0 = 32 * ks + (l >> 4) * 8;
    int col = 16 * ct + (l & 15);
#pragma unroll
    for (int j = 0; j < 8; j++) {
        float v = Wf[(size_t)col * FIN + k0 + j];
        ushort_t h = f2bf(v);
        size_t idx = ((size_t)fid * 64 + l) * 8 + j;
        Wfh[idx] = h;
        Wfl[idx] = f2bf(v - bf2f(h));
    }
}

// ---------- split-bf16 A-fragment conversion ----------

__device__ __forceinline__ void cvt8(float4 x, float4 y, short8v& hi, short8v& lo) {
    union { short8v v; ushort_t u[8]; } H, L;
    float f[8] = {x.x, x.y, x.z, x.w, y.x, y.y, y.z, y.w};
#pragma unroll
    for (int j = 0; j < 8; j++) {
        ushort_t h = f2bf(f[j]);
        H.u[j] = h;
        L.u[j] = f2bf(f[j] - bf2f(h));
    }
    hi = H.v; lo = L.v;
}

// ---------- initial linear via MFMA: h = relu(x @ Wf^T + bf) ----------
// One wave per 16 rows; A = x split hi/lo in regs; 6 col-tiles x 4 k-steps.

__global__ __launch_bounds__(64) void lin_mfma(const float* __restrict__ x,
                             const ushort_t* __restrict__ Wfh, const ushort_t* __restrict__ Wfl,
                             const float* __restrict__ bf, float* __restrict__ h, int N) {
    int l = threadIdx.x;
    int n0 = blockIdx.x * 16;
    int row = n0 + (l & 15);
    if (row >= N) row = N - 1;
    const float* xrow = x + (size_t)row * FIN + ((l >> 4) * 8);

    short8v ah[4], al[4];
#pragma unroll
    for (int ks = 0; ks < 4; ks++) {
        float4 xa = *(const float4*)(xrow + 32 * ks);
        float4 xb = *(const float4*)(xrow + 32 * ks + 4);
        cvt8(xa, xb, ah[ks], al[ks]);
    }

    for (int ct = 0; ct < 6; ct++) {
        f32x4 ahh = {0.f, 0.f, 0.f, 0.f};
        f32x4 ahl = {0.f, 0.f, 0.f, 0.f};
        f32x4 alh = {0.f, 0.f, 0.f, 0.f};
#pragma unroll
        for (int ks = 0; ks < 4; ks++) {
            const size_t base = ((size_t)(ct * 4 + ks) * 64 + l) * 8;
            short8v bh = *(const short8v*)(Wfh + base);
            short8v bl = *(const short8v*)(Wfl + base);
            ahh = MFMA16(ah[ks], bh, ahh, 0, 0, 0);
            ahl = MFMA16(ah[ks], bl, ahl, 0, 0, 0);
            alh = MFMA16(al[ks], bh, alh, 0, 0, 0);
        }
        f32x4 acc = ahh + ahl + alh;
        int col = ct * 16 + (l & 15);
        int mb = n0 + ((l >> 4) << 2);
        float bv = bf[col];
#pragma unroll
        for (int r = 0; r < 4; r++) {
            int m = mb + r;
            if (m < N) {
                float v = acc[r] + bv;
                h[(size_t)m * DN + col] = v > 0.f ? v : 0.f;
            }
        }
    }
}

// ---------- gemm via MFMA: hroot = h@root + bias (in place); g0/g1 = bf16(h@W0/1) ----------

__global__ __launch_bounds__(64) void gemm_mfma(float* hb,
                              const ushort_t* __restrict__ Bph, const ushort_t* __restrict__ Bpl,
                              ushort_t* __restrict__ g0, ushort_t* __restrict__ g1,
                              const float* __restrict__ bias, int N) {
    int l = threadIdx.x;          // 0..63
    int n0 = blockIdx.x * 16;
    int row = n0 + (l & 15);
    if (row >= N) row = N - 1;    // clamp; tail rows unused on store
    const float* hrow = hb + (size_t)row * DN + ((l >> 4) * 8);

    short8v ah[3], al[3];
#pragma unroll
    for (int ks = 0; ks < 3; ks++) {
        float4 xa = *(const float4*)(hrow + 32 * ks);
        float4 xb = *(const float4*)(hrow + 32 * ks + 4);
        cvt8(xa, xb, ah[ks], al[ks]);
    }

    for (int ct = 0; ct < 18; ct++) {
        f32x4 ahh = {0.f, 0.f, 0.f, 0.f};
        f32x4 ahl = {0.f, 0.f, 0.f, 0.f};
        f32x4 alh = {0.f, 0.f, 0.f, 0.f};
#pragma unroll
        for (int ks = 0; ks < 3; ks++) {
            const size_t base = ((size_t)(ct * 3 + ks) * 64 + l) * 8;
            short8v bh = *(const short8v*)(Bph + base);
            short8v bl = *(const short8v*)(Bpl + base);
            ahh = MFMA16(ah[ks], bh, ahh, 0, 0, 0);
            ahl = MFMA16(ah[ks], bl, ahl, 0, 0, 0);
            alh = MFMA16(al[ks], bh, alh, 0, 0, 0);
        }
        f32x4 acc = ahh + ahl + alh;

        int mat = ct / 6;                       // uniform across wave
        int col = (ct % 6) * 16 + (l & 15);
        int mb = n0 + ((l >> 4) << 2);
        if (mat == 0) {
            float bv = bias[col];
#pragma unroll
            for (int r = 0; r < 4; r++) {
                int m = mb + r;
                if (m < N) hb[(size_t)m * DN + col] = acc[r] + bv;
            }
        } else {
            ushort_t* g = (mat == 1) ? g0 : g1;
#pragma unroll
            for (int r = 0; r < 4; r++) {
                int m = mb + r;
                if (m < N) g[(size_t)m * DN + col] = f2bf(acc[r]);
            }
        }
    }
}

// ---------- agg: out[n] = relu(hroot[n] + mean(g0[src in r0]) + mean(g1[src in r1])) ----------

__global__ __launch_bounds__(256) void agg_kernel(float* hb, const uint_t* __restrict__ g0,
                           const uint_t* __restrict__ g1, const int* __restrict__ rowstart,
                           const int* __restrict__ cnt, const int* __restrict__ srcs, int N) {
    int t = threadIdx.x;
    int hw = t >> 5;
    int m = t & 31;
    int n = blockIdx.x * NB + hw;
    if (n >= N || m >= 24) return;

    size_t off = (size_t)n * DN + 4 * m;
    float4 hv = *(const float4*)(hb + off);

    int b0 = rowstart[n], c0 = cnt[n];
    int b1 = rowstart[N + n], c1 = cnt[N + n];

    float acc0 = 0.f, acc1 = 0.f, acc2 = 0.f, acc3 = 0.f;
#pragma unroll
    for (int r = 0; r < 2; r++) {
        const uint_t* g = r ? g1 : g0;
        int base = r ? b1 : b0;
        int c = r ? c1 : c0;
        const int* sp = srcs + base;
        float s0 = 0.f, s1 = 0.f, s2 = 0.f, s3 = 0.f;
        int e = 0;
        for (; e + 4 <= c; e += 4) {
            int i0 = sp[e], i1 = sp[e + 1], i2 = sp[e + 2], i3 = sp[e + 3];
            uint2 v0 = *(const uint2*)(g + (size_t)i0 * 48 + 2 * m);
            uint2 v1 = *(const uint2*)(g + (size_t)i1 * 48 + 2 * m);
            uint2 v2 = *(const uint2*)(g + (size_t)i2 * 48 + 2 * m);
            uint2 v3 = *(const uint2*)(g + (size_t)i3 * 48 + 2 * m);
            s0 += (bf_lo(v0.x) + bf_lo(v1.x)) + (bf_lo(v2.x) + bf_lo(v3.x));
            s1 += (bf_hi(v0.x) + bf_hi(v1.x)) + (bf_hi(v2.x) + bf_hi(v3.x));
            s2 += (bf_lo(v0.y) + bf_lo(v1.y)) + (bf_lo(v2.y) + bf_lo(v3.y));
            s3 += (bf_hi(v0.y) + bf_hi(v1.y)) + (bf_hi(v2.y) + bf_hi(v3.y));
        }
        for (; e < c; e++) {
            uint2 v = *(const uint2*)(g + (size_t)sp[e] * 48 + 2 * m);
            s0 += bf_lo(v.x);
            s1 += bf_hi(v.x);
            s2 += bf_lo(v.y);
            s3 += bf_hi(v.y);
        }
        float inv = (c > 0) ? 1.f / (float)c : 0.f;
        acc0 += s0 * inv;
        acc1 += s1 * inv;
        acc2 += s2 * inv;
        acc3 += s3 * inv;
    }
    float4 o;
    o.x = hv.x + acc0; o.x = o.x > 0.f ? o.x : 0.f;
    o.y = hv.y + acc1; o.y = o.y > 0.f ? o.y : 0.f;
    o.z = hv.z + acc2; o.z = o.z > 0.f ? o.z : 0.f;
    o.w = hv.w + acc3; o.w = o.w > 0.f ? o.w : 0.f;
    *(float4*)(hb + off) = o;
}

extern "C" void kernel_launch(void* const* d_in, const int* in_sizes, int n_in,
                              void* d_out, int out_size, void* d_ws, size_t ws_size,
                              hipStream_t stream) {
    const float* x    = (const float*)d_in[0];
    const int*   ei   = (const int*)d_in[1];
    const float* ea   = (const float*)d_in[2];
    const float* Wf   = (const float*)d_in[3];
    const float* bf   = (const float*)d_in[4];
    const float* W    = (const float*)d_in[5];
    const float* root = (const float*)d_in[6];
    const float* bias = (const float*)d_in[7];
    float* out = (float*)d_out;

    int N = in_sizes[0] / FIN;  // 50000
    int E = in_sizes[1] / 2;    // 800000
    int nbins = 2 * N;
    int PS = (N + 7) / 8;       // dst partition size

    int* cnt      = (int*)d_ws;            // [2N]
    int* total    = cnt + nbins;           // [1]
    int* rowstart = cnt + nbins + 4;       // [2N]
    int* fillptr  = rowstart + nbins;      // [2N]
    int* srcs     = fillptr + nbins;       // [E]
    uint2* kd     = (uint2*)(srcs + E);    // [E] packed (dst|r, src)
    ushort_t* Bph = (ushort_t*)(kd + E);           // [54*64*8]
    ushort_t* Bpl = Bph + 54 * 64 * 8;             // [54*64*8]
    ushort_t* Wfh = Bpl + 54 * 64 * 8;             // [24*64*8]
    ushort_t* Wfl = Wfh + 24 * 64 * 8;             // [24*64*8]
    ushort_t* g0  = Wfl + 24 * 64 * 8;             // [N*96] bf16
    ushort_t* g1  = g0 + (size_t)N * DN;           // [N*96] bf16

    hipMemsetAsync(cnt, 0, (size_t)(nbins + 1) * sizeof(int), stream);

    hist_kernel<<<(E + 255) / 256, 256, 0, stream>>>(ei, ea, cnt, kd, E, N);
    offsets_kernel<<<(nbins + 255) / 256, 256, 0, stream>>>(cnt, total, rowstart, fillptr, nbins);
    int nchunk = (E + 2047) / 2048;
    fill_part<<<nchunk * 8, 256, 0, stream>>>(kd, fillptr, srcs, E, N, PS);
    pack_w<<<54, 64, 0, stream>>>(root, W, Bph, Bpl);
    pack_wf<<<24, 64, 0, stream>>>(Wf, Wfh, Wfl);

    int gblk = (N + 15) / 16;
    lin_mfma<<<gblk, 64, 0, stream>>>(x, Wfh, Wfl, bf, out, N);

    int nblk = (N + NB - 1) / NB;
    for (int lyr = 0; lyr < 3; lyr++) {
        gemm_mfma<<<gblk, 64, 0, stream>>>(out, Bph, Bpl, g0, g1, bias, N);
        agg_kernel<<<nblk, 256, 0, stream>>>(out, (const uint_t*)g0, (const uint_t*)g1,
                                             rowstart, cnt, srcs, N);
    }
}

// Round 6
// 294.303 us; speedup vs baseline: 3.1246x; 1.0860x over previous
//
#include <hip/hip_runtime.h>

#define DN 96
#define FIN 128

typedef unsigned int uint_t;
typedef unsigned short ushort_t;

typedef __attribute__((ext_vector_type(8))) short short8v;  // 8 bf16 (4 VGPRs)
typedef __attribute__((ext_vector_type(4))) float f32x4;

#define MFMA16 __builtin_amdgcn_mfma_f32_16x16x32_bf16

struct __align__(4) U3 { uint_t x, y, z; };

__device__ __forceinline__ ushort_t f2bf(float f) {
    uint_t u = __float_as_uint(f);
    uint_t r = (u + 0x7FFFu + ((u >> 16) & 1u)) >> 16;
    return (ushort_t)r;
}
__device__ __forceinline__ float bf2f(ushort_t h) { return __uint_as_float(((uint_t)h) << 16); }
__device__ __forceinline__ float bf_lo(uint_t u) { return __uint_as_float(u << 16); }
__device__ __forceinline__ float bf_hi(uint_t u) { return __uint_as_float(u & 0xFFFF0000u); }

// ---------- CSR build ----------
// hist: count per (rel,dst) bin; also emit packed kd[e] = {dst | r<<16, src}.

__global__ void hist_kernel(const int* __restrict__ ei, const float* __restrict__ ea,
                            int* __restrict__ cnt, uint2* __restrict__ kd, int E, int N) {
    int e = blockIdx.x * 256 + threadIdx.x;
    if (e >= E) return;
    int src = ei[e];
    int dst = ei[E + e];
    int r = (ea[2 * e + 1] > ea[2 * e]) ? 1 : 0;  // argmax over 2, first-max tie -> 0
    kd[e] = make_uint2((uint_t)dst | ((uint_t)r << 16), (uint_t)src);
    atomicAdd(&cnt[r * N + dst], 1);
}

__global__ void offsets_kernel(const int* __restrict__ cnt, int* __restrict__ total,
                               int* __restrict__ rowstart, int* __restrict__ fillptr,
                               int nbins) {
    __shared__ int sd[256];
    __shared__ int sbase;
    int t = threadIdx.x;
    int b = blockIdx.x * 256 + t;
    int v = (b < nbins) ? cnt[b] : 0;
    sd[t] = v;
    __syncthreads();
    for (int off = 1; off < 256; off <<= 1) {
        int add = (t >= off) ? sd[t - off] : 0;
        __syncthreads();
        sd[t] += add;
        __syncthreads();
    }
    if (t == 255) sbase = atomicAdd(total, sd[255]);
    __syncthreads();
    if (b < nbins) {
        int s = sbase + sd[t] - v;  // exclusive
        rowstart[b] = s;
        fillptr[b] = s;
    }
}

// XCD-partitioned fill (see round 5): srcs writes for a dst range come from one
// partition of blocks -> full-line L2 writebacks instead of 4B/64B amplification.

__global__ __launch_bounds__(256) void fill_part(const uint2* __restrict__ kd,
                            int* __restrict__ fillptr, int* __restrict__ srcs,
                            int E, int N, int PS) {
    int p = blockIdx.x & 7;
    int c = blockIdx.x >> 3;
    int base = c * 2048 + threadIdx.x;
#pragma unroll
    for (int i = 0; i < 8; i++) {
        int e = base + i * 256;
        if (e < E) {
            uint2 v = kd[e];
            int dst = v.x & 0xFFFF;
            if (dst / PS == p) {
                int r = (v.x >> 16) & 1;
                int pos = atomicAdd(&fillptr[r * N + dst], 1);
                srcs[pos] = (int)v.y;
            }
        }
    }
}

// ---------- weight pack: split bf16 hi/lo, MFMA B-fragment layout ----------
// Lane l of a frag holds B[k][col], col = 16*cw + (l&15), k = 32*ks + (l>>4)*8 + j,
// packed so each lane reads one contiguous 16B chunk.
// bid < 54: conv weights (fid = ct*3+ks; ct = mat*6+cw; 0=root,1=W0,2=W1)
// bid >= 54: lin weights B[k][col] = Wf[col][k] (fid = ct*4+ks)

__global__ void pack_all(const float* __restrict__ root, const float* __restrict__ W,
                         const float* __restrict__ Wf,
                         ushort_t* __restrict__ Bph, ushort_t* __restrict__ Bpl,
                         ushort_t* __restrict__ Wfh, ushort_t* __restrict__ Wfl) {
    int l = threadIdx.x;      // 0..63
    int bid = blockIdx.x;
    if (bid < 54) {
        int fid = bid;
        int ct = fid / 3, ks = fid % 3;
        int mat = ct / 6, cw = ct % 6;
        const float* M = (mat == 0) ? root : (W + (size_t)(mat - 1) * DN * DN);
        int k0 = 32 * ks + (l >> 4) * 8;
        int col = 16 * cw + (l & 15);
#pragma unroll
        for (int j = 0; j < 8; j++) {
            float v = M[(size_t)(k0 + j) * DN + col];
            ushort_t h = f2bf(v);
            size_t idx = ((size_t)fid * 64 + l) * 8 + j;
            Bph[idx] = h;
            Bpl[idx] = f2bf(v - bf2f(h));
        }
    } else {
        int fid = bid - 54;
        int ct = fid >> 2, ks = fid & 3;
        int k0 = 32 * ks + (l >> 4) * 8;
        int col = 16 * ct + (l & 15);
#pragma unroll
        for (int j = 0; j < 8; j++) {
            float v = Wf[(size_t)col * FIN + k0 + j];
            ushort_t h = f2bf(v);
            size_t idx = ((size_t)fid * 64 + l) * 8 + j;
            Wfh[idx] = h;
            Wfl[idx] = f2bf(v - bf2f(h));
        }
    }
}

// ---------- split-bf16 A-fragment conversion ----------

__device__ __forceinline__ void cvt8(float4 x, float4 y, short8v& hi, short8v& lo) {
    union { short8v v; ushort_t u[8]; } H, L;
    float f[8] = {x.x, x.y, x.z, x.w, y.x, y.y, y.z, y.w};
#pragma unroll
    for (int j = 0; j < 8; j++) {
        ushort_t h = f2bf(f[j]);
        H.u[j] = h;
        L.u[j] = f2bf(f[j] - bf2f(h));
    }
    hi = H.v; lo = L.v;
}

// ---------- fused layer kernel ----------
// MODE 0: h = relu(x@Wf^T+bf) (MFMA, wave-local 16-row slab, 64 nodes/block)
//         then gemm: hrootOut = h@root+bias, g0/g1Out = bf16(h@W0/1).
// MODE 1: out = relu(hrootIn + mean(g0In) + mean(g1In)) (gather, 16 nodes/block,
//         16 lanes/node x uint3), then gemm on out (18 col-tiles split over 4 waves).
// MODE 2: gather only, write d_out.
// A*B via split bf16: Ahi*Bhi + Ahi*Blo + Alo*Bhi ~ fp32 accuracy.

template <int MODE>
__global__ __launch_bounds__(256) void layer_kernel(
    const float* __restrict__ xin,
    const float* __restrict__ hrootIn,
    const uint_t* __restrict__ g0In, const uint_t* __restrict__ g1In,
    const int* __restrict__ rowstart, const int* __restrict__ cnt,
    const int* __restrict__ srcs,
    const ushort_t* __restrict__ WfH, const ushort_t* __restrict__ WfL,
    const ushort_t* __restrict__ Bph, const ushort_t* __restrict__ Bpl,
    const float* __restrict__ bfv, const float* __restrict__ bias,
    float* __restrict__ hrootOut, ushort_t* __restrict__ g0Out, ushort_t* __restrict__ g1Out,
    float* __restrict__ dout, int N)
{
    constexpr int NW = (MODE == 0) ? 4 : 1;
    __shared__ float sout[NW][16][100];   // +4 pad breaks power-of-2 bank stride
    int t = threadIdx.x;
    int l = t & 63;
    int w = t >> 6;

    if constexpr (MODE == 0) {
        // ---- lin phase: wave-local 16 rows via MFMA from x ----
        int slab = blockIdx.x * 64 + w * 16;
        int row = slab + (l & 15);
        if (row >= N) row = N - 1;
        const float* xrow = xin + (size_t)row * FIN + ((l >> 4) * 8);
        short8v ah[4], al[4];
#pragma unroll
        for (int ks = 0; ks < 4; ks++) {
            float4 xa = *(const float4*)(xrow + 32 * ks);
            float4 xb = *(const float4*)(xrow + 32 * ks + 4);
            cvt8(xa, xb, ah[ks], al[ks]);
        }
#pragma unroll
        for (int ct = 0; ct < 6; ct++) {
            f32x4 hh = {0.f,0.f,0.f,0.f}, hl_ = {0.f,0.f,0.f,0.f}, lh = {0.f,0.f,0.f,0.f};
#pragma unroll
            for (int ks = 0; ks < 4; ks++) {
                size_t base = ((size_t)(ct * 4 + ks) * 64 + l) * 8;
                short8v bh = *(const short8v*)(WfH + base);
                short8v bl = *(const short8v*)(WfL + base);
                hh  = MFMA16(ah[ks], bh, hh, 0, 0, 0);
                hl_ = MFMA16(ah[ks], bl, hl_, 0, 0, 0);
                lh  = MFMA16(al[ks], bh, lh, 0, 0, 0);
            }
            f32x4 acc = hh + hl_ + lh;
            int col = ct * 16 + (l & 15);
            float bv = bfv[col];
            int lr0 = (l >> 4) * 4;
#pragma unroll
            for (int r = 0; r < 4; r++) {
                float v = acc[r] + bv;
                sout[w][lr0 + r][col] = v > 0.f ? v : 0.f;
            }
        }
    } else {
        // ---- gather phase: 16 groups of 16 lanes, one node each ----
        int grp = t >> 4;
        int j = t & 15;
        int n = blockIdx.x * 16 + grp;
        bool valid = n < N;
        int nc = valid ? n : N - 1;
        float a0=0.f,a1=0.f,a2=0.f,a3=0.f,a4=0.f,a5=0.f;
#pragma unroll
        for (int r = 0; r < 2; r++) {
            int c    = valid ? cnt[r * N + nc] : 0;
            int base = valid ? rowstart[r * N + nc] : 0;
            const uint_t* g = r ? g1In : g0In;
            const int* sp = srcs + base;
            float s0=0.f,s1=0.f,s2=0.f,s3=0.f,s4=0.f,s5=0.f;
            int e = 0;
            for (; e + 4 <= c; e += 4) {
                int i0 = sp[e], i1 = sp[e+1], i2 = sp[e+2], i3 = sp[e+3];
                U3 v0 = *(const U3*)(g + (size_t)i0 * 48 + 3 * j);
                U3 v1 = *(const U3*)(g + (size_t)i1 * 48 + 3 * j);
                U3 v2 = *(const U3*)(g + (size_t)i2 * 48 + 3 * j);
                U3 v3 = *(const U3*)(g + (size_t)i3 * 48 + 3 * j);
                s0 += (bf_lo(v0.x) + bf_lo(v1.x)) + (bf_lo(v2.x) + bf_lo(v3.x));
                s1 += (bf_hi(v0.x) + bf_hi(v1.x)) + (bf_hi(v2.x) + bf_hi(v3.x));
                s2 += (bf_lo(v0.y) + bf_lo(v1.y)) + (bf_lo(v2.y) + bf_lo(v3.y));
                s3 += (bf_hi(v0.y) + bf_hi(v1.y)) + (bf_hi(v2.y) + bf_hi(v3.y));
                s4 += (bf_lo(v0.z) + bf_lo(v1.z)) + (bf_lo(v2.z) + bf_lo(v3.z));
                s5 += (bf_hi(v0.z) + bf_hi(v1.z)) + (bf_hi(v2.z) + bf_hi(v3.z));
            }
            for (; e < c; e++) {
                U3 v = *(const U3*)(g + (size_t)sp[e] * 48 + 3 * j);
                s0 += bf_lo(v.x); s1 += bf_hi(v.x);
                s2 += bf_lo(v.y); s3 += bf_hi(v.y);
                s4 += bf_lo(v.z); s5 += bf_hi(v.z);
            }
            float inv = (c > 0) ? 1.f / (float)c : 0.f;
            a0 += s0 * inv; a1 += s1 * inv; a2 += s2 * inv;
            a3 += s3 * inv; a4 += s4 * inv; a5 += s5 * inv;
        }
        const float* hr = hrootIn + (size_t)nc * DN + 6 * j;
        float2 p0 = *(const float2*)hr;
        float2 p1 = *(const float2*)(hr + 2);
        float2 p2 = *(const float2*)(hr + 4);
        float o0 = fmaxf(p0.x + a0, 0.f);
        float o1 = fmaxf(p0.y + a1, 0.f);
        float o2 = fmaxf(p1.x + a2, 0.f);
        float o3 = fmaxf(p1.y + a3, 0.f);
        float o4 = fmaxf(p2.x + a4, 0.f);
        float o5 = fmaxf(p2.y + a5, 0.f);
        if constexpr (MODE == 1) {
            float* dr = &sout[0][grp][6 * j];
            dr[0]=o0; dr[1]=o1; dr[2]=o2; dr[3]=o3; dr[4]=o4; dr[5]=o5;
        } else {
            if (valid) {
                float* dr = dout + (size_t)n * DN + 6 * j;
                *(float2*)(dr)     = make_float2(o0, o1);
                *(float2*)(dr + 2) = make_float2(o2, o3);
                *(float2*)(dr + 4) = make_float2(o4, o5);
            }
        }
    }

    if constexpr (MODE == 2) return;
    __syncthreads();

    // ---- gemm phase: A from LDS, 18 col-tiles ----
    {
        const float* srow;
        int mbase;
        if constexpr (MODE == 0) {
            srow = &sout[w][l & 15][0];
            mbase = blockIdx.x * 64 + w * 16 + ((l >> 4) << 2);
        } else {
            srow = &sout[0][l & 15][0];
            mbase = blockIdx.x * 16 + ((l >> 4) << 2);
        }
        int k0 = (l >> 4) * 8;
        short8v ah[3], al[3];
#pragma unroll
        for (int ks = 0; ks < 3; ks++) {
            float4 xa = *(const float4*)(srow + k0 + 32 * ks);
            float4 xb = *(const float4*)(srow + k0 + 32 * ks + 4);
            cvt8(xa, xb, ah[ks], al[ks]);
        }
        int ctS, ctC;
        if constexpr (MODE == 0) { ctS = 0; ctC = 18; }
        else { ctS = (w < 2) ? 5 * w : 10 + 4 * (w - 2); ctC = (w < 2) ? 5 : 4; }
        for (int ci = 0; ci < ctC; ci++) {
            int ct = ctS + ci;
            f32x4 hh = {0.f,0.f,0.f,0.f}, hl_ = {0.f,0.f,0.f,0.f}, lh = {0.f,0.f,0.f,0.f};
#pragma unroll
            for (int ks = 0; ks < 3; ks++) {
                size_t base = ((size_t)(ct * 3 + ks) * 64 + l) * 8;
                short8v bh = *(const short8v*)(Bph + base);
                short8v bl = *(const short8v*)(Bpl + base);
                hh  = MFMA16(ah[ks], bh, hh, 0, 0, 0);
                hl_ = MFMA16(ah[ks], bl, hl_, 0, 0, 0);
                lh  = MFMA16(al[ks], bh, lh, 0, 0, 0);
            }
            f32x4 acc = hh + hl_ + lh;
            int mat = ct / 6;
            int col = (ct % 6) * 16 + (l & 15);
            if (mat == 0) {
                float bv = bias[col];
#pragma unroll
                for (int r = 0; r < 4; r++) {
                    int m = mbase + r;
                    if (m < N) hrootOut[(size_t)m * DN + col] = acc[r] + bv;
                }
            } else {
                ushort_t* g = (mat == 1) ? g0Out : g1Out;
#pragma unroll
                for (int r = 0; r < 4; r++) {
                    int m = mbase + r;
                    if (m < N) g[(size_t)m * DN + col] = f2bf(acc[r]);
                }
            }
        }
    }
}

extern "C" void kernel_launch(void* const* d_in, const int* in_sizes, int n_in,
                              void* d_out, int out_size, void* d_ws, size_t ws_size,
                              hipStream_t stream) {
    const float* x    = (const float*)d_in[0];
    const int*   ei   = (const int*)d_in[1];
    const float* ea   = (const float*)d_in[2];
    const float* Wf   = (const float*)d_in[3];
    const float* bf   = (const float*)d_in[4];
    const float* W    = (const float*)d_in[5];
    const float* root = (const float*)d_in[6];
    const float* bias = (const float*)d_in[7];
    float* out = (float*)d_out;

    int N = in_sizes[0] / FIN;  // 50000
    int E = in_sizes[1] / 2;    // 800000
    int nbins = 2 * N;
    int PS = (N + 7) / 8;       // dst partition size

    int* cnt      = (int*)d_ws;            // [2N]
    int* total    = cnt + nbins;           // [1]
    int* rowstart = cnt + nbins + 4;       // [2N]
    int* fillptr  = rowstart + nbins;      // [2N]
    int* srcs     = fillptr + nbins;       // [E]
    uint2* kd     = (uint2*)(srcs + E);    // [E] packed (dst|r, src)
    ushort_t* Bph = (ushort_t*)(kd + E);   // [54*512]
    ushort_t* Bpl = Bph + 54 * 512;        // [54*512]
    ushort_t* Wfh = Bpl + 54 * 512;        // [24*512]
    ushort_t* Wfl = Wfh + 24 * 512;        // [24*512]
    float* hrootA = (float*)(Wfl + 24 * 512);      // [N*96] f32
    ushort_t* g0A = (ushort_t*)(hrootA + (size_t)N * DN);  // [N*96] bf16
    ushort_t* g1A = g0A + (size_t)N * DN;
    float* hrootB = (float*)(g1A + (size_t)N * DN);        // [N*96] f32
    ushort_t* g0B = (ushort_t*)(hrootB + (size_t)N * DN);
    ushort_t* g1B = g0B + (size_t)N * DN;

    hipMemsetAsync(cnt, 0, (size_t)(nbins + 1) * sizeof(int), stream);

    hist_kernel<<<(E + 255) / 256, 256, 0, stream>>>(ei, ea, cnt, kd, E, N);
    offsets_kernel<<<(nbins + 255) / 256, 256, 0, stream>>>(cnt, total, rowstart, fillptr, nbins);
    int nchunk = (E + 2047) / 2048;
    fill_part<<<nchunk * 8, 256, 0, stream>>>(kd, fillptr, srcs, E, N, PS);
    pack_all<<<78, 64, 0, stream>>>(root, W, Wf, Bph, Bpl, Wfh, Wfl);

    int blk64 = (N + 63) / 64;
    int blk16 = (N + 15) / 16;

    // L0: lin+gemm from x -> set A
    layer_kernel<0><<<blk64, 256, 0, stream>>>(
        x, nullptr, nullptr, nullptr, rowstart, cnt, srcs,
        Wfh, Wfl, Bph, Bpl, bf, bias, hrootA, g0A, g1A, nullptr, N);
    // L1: gather A -> gemm -> set B
    layer_kernel<1><<<blk16, 256, 0, stream>>>(
        nullptr, hrootA, (const uint_t*)g0A, (const uint_t*)g1A, rowstart, cnt, srcs,
        nullptr, nullptr, Bph, Bpl, nullptr, bias, hrootB, g0B, g1B, nullptr, N);
    // L2: gather B -> gemm -> set A
    layer_kernel<1><<<blk16, 256, 0, stream>>>(
        nullptr, hrootB, (const uint_t*)g0B, (const uint_t*)g1B, rowstart, cnt, srcs,
        nullptr, nullptr, Bph, Bpl, nullptr, bias, hrootA, g0A, g1A, nullptr, N);
    // L3: gather A -> d_out
    layer_kernel<2><<<blk16, 256, 0, stream>>>(
        nullptr, hrootA, (const uint_t*)g0A, (const uint_t*)g1A, rowstart, cnt, srcs,
        nullptr, nullptr, nullptr, nullptr, nullptr, nullptr, nullptr, nullptr, nullptr, out, N);
}